// Round 10
// baseline (1039.695 us; speedup 1.0000x reference)
//
#include <hip/hip_runtime.h>
#include <hip/hip_bf16.h>
#include <math.h>

#define B_ 4
#define T_ 2048
#define C_ 2048
#define H_ 32
#define BT_ 8192
#define WELE 4194304L            // 2048*2048
#define BTC  16777216L           // 8192*2048
#define NCH_ 16                  // chunks along T for wkv parallel scan
#define TC_  128                 // T_/NCH_
#define GNT  32                  // K/64 for the 256^2 GEMM (K=2048)

typedef unsigned short u16;
typedef __bf16 bf16x8 __attribute__((ext_vector_type(8)));
typedef float  f32x4  __attribute__((ext_vector_type(4)));

__device__ __forceinline__ u16 f2b(float f){
  __hip_bfloat16 h = __float2bfloat16(f);
  return *reinterpret_cast<u16*>(&h);
}
__device__ __forceinline__ float b2f(u16 u){
  __hip_bfloat16 h; *reinterpret_cast<u16*>(&h) = u;
  return __bfloat162float(h);
}
__device__ __forceinline__ float bits2f(unsigned u){
  union { unsigned u; float f; } c; c.u = u; return c.f;
}

__device__ __forceinline__ void async_copy16(const u16* gptr, u16* lptr){
  __builtin_amdgcn_global_load_lds(
      (const __attribute__((address_space(1))) unsigned int*)gptr,
      (__attribute__((address_space(3))) unsigned int*)lptr,
      16, 0, 0);
}

// unpack 4 consecutive bf16 at gp into 4 floats
__device__ __forceinline__ void unpack4(const u16* __restrict__ gp, float* out){
  const uint2 raw = *(const uint2*)gp;
  out[0] = bits2f(raw.x << 16); out[1] = bits2f(raw.x & 0xffff0000u);
  out[2] = bits2f(raw.y << 16); out[3] = bits2f(raw.y & 0xffff0000u);
}

// ---------------- weight prep ----------------
__global__ __launch_bounds__(256) void cvt1(const float* __restrict__ src,
                                            u16* __restrict__ dst)
{
  const long i = ((long)blockIdx.x*256 + threadIdx.x)*4;
  const float4 v = *(const float4*)(src + i);
  ushort4 o = { f2b(v.x), f2b(v.y), f2b(v.z), f2b(v.w) };
  *(ushort4*)(dst + i) = o;
}

__global__ __launch_bounds__(256) void tposeA(const float* __restrict__ src,
    u16* __restrict__ dst, int R, int Cc, int Npad)
{
  const long idx = (long)blockIdx.x*256 + threadIdx.x;
  if (idx >= (long)Npad * R) return;
  const int n = (int)(idx / R), rr = (int)(idx % R);
  float vv = (n < Cc) ? src[(long)rr * Cc + n] : 0.f;
  dst[idx] = f2b(vv);
}

__global__ __launch_bounds__(256) void tposeW2(const float* __restrict__ src,
                                               u16* __restrict__ dst)
{
  const long idx = (long)blockIdx.x*256 + threadIdx.x; // < 5*2048*32
  const int f = (int)(idx / 65536);
  const int rem = (int)(idx % 65536);
  const int c = rem >> 5, d = rem & 31;
  dst[idx] = f2b(src[((long)f*32 + d)*2048 + c]);
}

// ---------------- token shift / xxx ----------------
__global__ __launch_bounds__(256) void mixA(const float* __restrict__ x,
    const float* __restrict__ maax, u16* __restrict__ xxx, u16* __restrict__ xxb,
    u16* __restrict__ xbf)
{
  const long i = ((long)blockIdx.x*256 + threadIdx.x) * 4;
  const int c   = (int)(i & (C_-1));
  const int tok = (int)(i >> 11);
  const int t   = tok & (T_-1);
  const float4 xc = *(const float4*)(x + i);
  float4 xp = make_float4(0.f,0.f,0.f,0.f);
  if (t > 0) xp = *(const float4*)(x + i - C_);
  const float4 mx = *(const float4*)(maax + c);
  const float xx0 = xp.x - xc.x, xx1 = xp.y - xc.y;
  const float xx2 = xp.z - xc.z, xx3 = xp.w - xc.w;
  ushort4 ox = { f2b(xx0), f2b(xx1), f2b(xx2), f2b(xx3) };
  ushort4 o3 = { f2b(fmaf(xx0, mx.x, xc.x)), f2b(fmaf(xx1, mx.y, xc.y)),
                 f2b(fmaf(xx2, mx.z, xc.z)), f2b(fmaf(xx3, mx.w, xc.w)) };
  ushort4 oxb = { f2b(xc.x), f2b(xc.y), f2b(xc.z), f2b(xc.w) };
  *(ushort4*)(xxb + i) = ox;
  *(ushort4*)(xxx + i) = o3;
  *(ushort4*)(xbf + i) = oxb;
}

// ---------------- GEMM epilogues ----------------
enum { EPI_BF16=0, EPI_TANH=1, EPI_SILU=2, EPI_MIX=3, EPI_DECAY=4, EPI_F32=5 };

// ---------------- small GEMM (128^2 tile): K<=64 mix/decay cases ----------
template<int EPI>
__global__ __launch_bounds__(256) void gemm_bt(
    const u16* __restrict__ A, int lda,
    const u16* __restrict__ Bm, int ldb, int K,
    void* __restrict__ Out, int ldo,
    const float* __restrict__ aux0, const u16* __restrict__ aux1,
    const float* __restrict__ aux2)
{
  __shared__ u16 As[128*32];
  __shared__ u16 Bs[128*32];
  const int tid = threadIdx.x;
  const int w = tid >> 6, lane = tid & 63;
  const int m0 = blockIdx.y * 128, n0 = blockIdx.x * 128;
  const int wm = w >> 1, wn = w & 1;
  const int rowA = lane >> 2, chunk = lane & 3;
  f32x4 acc[4][4];
  #pragma unroll
  for (int i=0;i<4;i++)
    #pragma unroll
    for (int j=0;j<4;j++) acc[i][j] = (f32x4){0.f,0.f,0.f,0.f};

  for (int k0 = 0; k0 < K; k0 += 32){
    #pragma unroll
    for (int s=0; s<2; s++){
      const int seg = w*2 + s;
      const int row = seg*16 + rowA;
      async_copy16(A  + (long)(m0+row)*lda + k0 + chunk*8, As + seg*512);
      async_copy16(Bm + (long)(n0+row)*ldb + k0 + chunk*8, Bs + seg*512);
    }
    __syncthreads();
    const int kq = (lane >> 4) * 8;
    const int lr16 = lane & 15;
    bf16x8 af[4], bfr[4];
    #pragma unroll
    for (int mt=0; mt<4; mt++)
      af[mt] = *(const bf16x8*)(As + (wm*64 + mt*16 + lr16)*32 + kq);
    #pragma unroll
    for (int nt=0; nt<4; nt++)
      bfr[nt] = *(const bf16x8*)(Bs + (wn*64 + nt*16 + lr16)*32 + kq);
    #pragma unroll
    for (int mt=0; mt<4; mt++)
      #pragma unroll
      for (int nt=0; nt<4; nt++)
        acc[mt][nt] = __builtin_amdgcn_mfma_f32_16x16x32_bf16(af[mt], bfr[nt], acc[mt][nt], 0, 0, 0);
    __syncthreads();
  }

  const int cr = lane & 15, cq = lane >> 4;
  #pragma unroll
  for (int mt=0; mt<4; mt++){
    #pragma unroll
    for (int nt=0; nt<4; nt++){
      #pragma unroll
      for (int rr=0; rr<4; rr++){
        const int row = m0 + wm*64 + mt*16 + cq*4 + rr;
        const int col = n0 + wn*64 + nt*16 + cr;
        const long oi = (long)row*ldo + col;
        const float val = acc[mt][nt][rr];
        if constexpr (EPI == EPI_F32){
          ((float*)Out)[oi] = val;
        } else if constexpr (EPI == EPI_BF16){
          ((u16*)Out)[oi] = f2b(val);
        } else if constexpr (EPI == EPI_TANH){
          ((u16*)Out)[oi] = f2b(tanhf(val));
        } else if constexpr (EPI == EPI_SILU){
          ((u16*)Out)[oi] = f2b(val / (1.f + expf(-val)));
        } else if constexpr (EPI == EPI_MIX){
          const float xv  = b2f(((const u16*)aux0)[oi]);   // bf16 x (R6)
          const float xxv = b2f(aux1[oi]);
          ((u16*)Out)[oi] = f2b(fmaf(xxv, aux2[col] + val, xv));
        } else { // EPI_DECAY
          ((float*)Out)[oi] = expf(-expf(val + aux0[col]));
        }
      }
    }
  }
}

// ---------------- skinny GEMM (64x128 tile): R10 ----------------
// For long-K, small-N GEMMs whose 128^2 grid underfills the machine:
// a-GEMM (M=8192,N=256,K=2048): dim3(2,64)=128 blocks -> dim3(2,128)=256.
// tanh-GEMM (N=128): dim3(1,64)=64 blocks -> dim3(1,128)=128.
// Same k-chunk order and per-element MFMA sequence as gemm_bt -> bit-identical.
// 4 waves as 2x2 quadrants of 32x64; LDS 12KB.
template<int EPI>
__global__ __launch_bounds__(256) void gemm_bt64(
    const u16* __restrict__ A, int lda,
    const u16* __restrict__ Bm, int ldb, int K,
    void* __restrict__ Out, int ldo)
{
  __shared__ u16 As[64*32];
  __shared__ u16 Bs[128*32];
  const int tid = threadIdx.x;
  const int w = tid >> 6, lane = tid & 63;
  const int m0 = blockIdx.y * 64, n0 = blockIdx.x * 128;
  const int wm = w >> 1, wn = w & 1;       // 32-row x 64-col quadrants
  const int rowA = lane >> 2, chunk = lane & 3;
  f32x4 acc[2][4];
  #pragma unroll
  for (int i=0;i<2;i++)
    #pragma unroll
    for (int j=0;j<4;j++) acc[i][j] = (f32x4){0.f,0.f,0.f,0.f};

  for (int k0 = 0; k0 < K; k0 += 32){
    {   // A: 4 segs of 16 rows, one per wave
      const int row = w*16 + rowA;
      async_copy16(A + (long)(m0+row)*lda + k0 + chunk*8, As + w*512);
    }
    #pragma unroll
    for (int s=0; s<2; s++){   // B: 8 segs, two per wave
      const int seg = w*2 + s;
      const int row = seg*16 + rowA;
      async_copy16(Bm + (long)(n0+row)*ldb + k0 + chunk*8, Bs + seg*512);
    }
    __syncthreads();
    const int kq = (lane >> 4) * 8;
    const int lr16 = lane & 15;
    bf16x8 af[2], bfr[4];
    #pragma unroll
    for (int mt=0; mt<2; mt++)
      af[mt] = *(const bf16x8*)(As + (wm*32 + mt*16 + lr16)*32 + kq);
    #pragma unroll
    for (int nt=0; nt<4; nt++)
      bfr[nt] = *(const bf16x8*)(Bs + (wn*64 + nt*16 + lr16)*32 + kq);
    #pragma unroll
    for (int mt=0; mt<2; mt++)
      #pragma unroll
      for (int nt=0; nt<4; nt++)
        acc[mt][nt] = __builtin_amdgcn_mfma_f32_16x16x32_bf16(af[mt], bfr[nt], acc[mt][nt], 0, 0, 0);
    __syncthreads();
  }

  const int cr = lane & 15, cq = lane >> 4;
  #pragma unroll
  for (int mt=0; mt<2; mt++){
    #pragma unroll
    for (int nt=0; nt<4; nt++){
      #pragma unroll
      for (int rr=0; rr<4; rr++){
        const int row = m0 + wm*32 + mt*16 + cq*4 + rr;
        const int col = n0 + wn*64 + nt*16 + cr;
        const long oi = (long)row*ldo + col;
        const float val = acc[mt][nt][rr];
        if constexpr (EPI == EPI_TANH){
          ((u16*)Out)[oi] = f2b(tanhf(val));
        } else {
          ((u16*)Out)[oi] = f2b(val);
        }
      }
    }
  }
}

// ---------------- big GEMM: 256^2 tile, BK=64, phase-pipelined --------------
// (unchanged from R4: best-measured config)
template<int EPI>
__global__ __launch_bounds__(512) void gemm256(
    const u16* __restrict__ A, const u16* __restrict__ Bm,
    void* __restrict__ Out, int ldo)
{
  __shared__ u16 lds[65536];     // [A buf0][A buf1][B buf0][B buf1], 16384 each
  const int tid  = threadIdx.x;
  const int w    = tid >> 6, lane = tid & 63;
  const int wm   = w >> 2, wn = w & 3;           // 2 x 4 waves
  const long m0  = (long)blockIdx.y * 256;
  const long n0  = (long)blockIdx.x * 256;

  auto stage_half = [&](u16* ldsbase, const u16* gb){
    const int rsub = lane >> 3;                  // 0..7
    const int c16  = (lane & 7) ^ rsub;          // inverse swizzle (involution)
    #pragma unroll
    for (int r2 = 0; r2 < 2; ++r2){
      const int row = (r2*8 + w)*8 + rsub;
      async_copy16(gb + (long)row*2048 + c16*8,
                   ldsbase + (r2*8 + w)*512);
    }
  };
  auto stage = [&](int t, int half){
    if (t >= GNT) return;
    const int b = t & 1;
    const long k0 = (long)t * 64;
    if      (half == 0) stage_half(lds + 32768 + b*16384,        Bm + n0*2048 + k0);
    else if (half == 1) stage_half(lds + 32768 + b*16384 + 8192, Bm + (n0+128)*2048 + k0);
    else if (half == 2) stage_half(lds + b*16384,                A  + m0*2048 + k0);
    else                stage_half(lds + b*16384 + 8192,         A  + (m0+128)*2048 + k0);
  };

  const int lr16 = lane & 15;
  const int kq   = lane >> 4;                    // 0..3
  auto aslot = [&](int buf, int row, int c16)->const u16*{
    return lds + buf*16384 + row*64 + ((c16 ^ (row & 7)) << 3);
  };
  auto bslot = [&](int buf, int row, int c16)->const u16*{
    return lds + 32768 + buf*16384 + row*64 + ((c16 ^ (row & 7)) << 3);
  };

  f32x4 acc[8][4];
  #pragma unroll
  for (int i=0;i<8;i++)
    #pragma unroll
    for (int j=0;j<4;j++) acc[i][j] = (f32x4){0.f,0.f,0.f,0.f};

  stage(0,0); stage(0,1); stage(0,2); stage(0,3);
  stage(1,0); stage(1,1); stage(1,2);
  asm volatile("s_waitcnt vmcnt(6)");
  asm volatile("" ::: "memory");
  __builtin_amdgcn_s_barrier();

  for (int t = 0; t < GNT; ++t){
    const int buf = t & 1;
    bf16x8 bfr[4][2];
    #pragma unroll
    for (int p = 0; p < 4; ++p){
      if (p == 0){
        #pragma unroll
        for (int nt=0; nt<4; nt++)
          #pragma unroll
          for (int kk=0; kk<2; kk++)
            bfr[nt][kk] = *(const bf16x8*)bslot(buf, wn*64 + nt*16 + lr16, kk*4 + kq);
      }
      bf16x8 af[2][2];
      #pragma unroll
      for (int i=0; i<2; i++)
        #pragma unroll
        for (int kk=0; kk<2; kk++)
          af[i][kk] = *(const bf16x8*)aslot(buf, wm*128 + (2*p+i)*16 + lr16, kk*4 + kq);
      if (p == 0) stage(t+1, 3);
      else        stage(t+2, p-1);
      if (p == 3){
        if (t <= GNT-3) asm volatile("s_waitcnt vmcnt(6)");
        else            asm volatile("s_waitcnt vmcnt(0)");
      }
      asm volatile("" ::: "memory");
      __builtin_amdgcn_s_barrier();
      __builtin_amdgcn_s_setprio(1);
      #pragma unroll
      for (int i=0; i<2; i++)
        #pragma unroll
        for (int nt=0; nt<4; nt++)
          #pragma unroll
          for (int kk=0; kk<2; kk++)
            acc[2*p+i][nt] = __builtin_amdgcn_mfma_f32_16x16x32_bf16(
                af[i][kk], bfr[nt][kk], acc[2*p+i][nt], 0, 0, 0);
      __builtin_amdgcn_s_setprio(0);
    }
  }

  const int cr = lane & 15, cq = lane >> 4;
  #pragma unroll
  for (int mt=0; mt<8; mt++){
    #pragma unroll
    for (int nt=0; nt<4; nt++){
      #pragma unroll
      for (int rr=0; rr<4; rr++){
        const long row = m0 + wm*128 + mt*16 + cq*4 + rr;
        const long col = n0 + wn*64 + nt*16 + cr;
        const long oi  = row*ldo + col;
        const float val = acc[mt][nt][rr];
        if constexpr (EPI == EPI_F32){
          ((float*)Out)[oi] = val;
        } else if constexpr (EPI == EPI_BF16){
          ((u16*)Out)[oi] = f2b(val);
        } else { // EPI_SILU
          ((u16*)Out)[oi] = f2b(val / (1.f + expf(-val)));
        }
      }
    }
  }
}

// ---------------- WKV6: exact chunk-parallel scan ----------------
// pass1/pass2 from R5; pass3 = R7 2-fma scan (best measured; 4-fma/2-fma/MFMA
// all land within +-5% of ~172us -> latency-structure-bound, declared done).

__global__ __launch_bounds__(256) void wkv_pass1(
    const u16* __restrict__ k, const u16* __restrict__ v,
    const float* __restrict__ dec,
    float* __restrict__ Sbuf, float* __restrict__ Dbuf)
{
  const int blk = blockIdx.x;            // bh*NCH_ + c
  const int c  = blk & (NCH_-1);
  if (c == NCH_-1) return;               // last chunk's S_loc/D never used
  const int bh = blk >> 4;
  const int b = bh >> 5, h = bh & 31;
  const int tid = threadIdx.x;
  const int g = tid >> 6, lane = tid & 63;   // phase A: lane = channel j, g = t-group
  const int hoff = h * 64;
  const long base0 = ((long)b * T_) * C_ + hoff;
  const int tA = c * TC_;

  __shared__ float kts[128][64];   // kappa~[t][j] = k*suffix, fp32 (32KB)
  __shared__ u16   vsh[128][64];   // raw bf16 v (16KB)
  __shared__ float Gp[4][64];      // 32-step group products

  #pragma unroll
  for (int rd = 0; rd < 4; ++rd){
    const int row0 = (rd*4 + g) * 8;
    async_copy16(v + base0 + (long)(tA + row0 + (lane>>3))*C_ + (lane&7)*8,
                 &vsh[row0][0]);
  }

  float d[32];
  float gp = 1.f;
  #pragma unroll
  for (int tau = 0; tau < 32; ++tau){
    d[tau] = dec[base0 + (long)(tA + g*32 + tau)*C_ + lane];
    gp *= d[tau];
  }
  Gp[g][lane] = gp;
  __syncthreads();
  float CS = 1.f;
  #pragma unroll
  for (int gg = 0; gg < 4; ++gg)
    if (gg > g) CS *= Gp[gg][lane];
  if (g == 0){
    Dbuf[(long)blk*64 + lane] =
        Gp[0][lane]*Gp[1][lane]*Gp[2][lane]*Gp[3][lane];
  }
  {
    float R = CS;
    #pragma unroll
    for (int tau = 31; tau >= 0; --tau){
      const float kv = b2f(k[base0 + (long)(tA + g*32 + tau)*C_ + lane]);
      kts[g*32 + tau][lane] = kv * R;
      R *= d[tau];
    }
  }
  __syncthreads();

  const int joff = g * 16;
  float S[16];
  #pragma unroll
  for (int jj=0;jj<16;jj++) S[jj]=0.f;
  #pragma unroll 4
  for (int t = 0; t < TC_; ++t){
    float kv[16];
    #pragma unroll
    for (int q=0;q<4;q++)
      *(float4*)(kv+q*4) = *(const float4*)&kts[t][joff+q*4];
    const float vi = b2f(vsh[t][lane]);
    #pragma unroll
    for (int jj=0;jj<16;jj++)
      S[jj] = fmaf(kv[jj], vi, S[jj]);
  }
  float* Sp = Sbuf + (long)blk*4096 + (long)joff*64 + lane;
  #pragma unroll
  for (int jj=0;jj<16;jj++) Sp[jj*64] = S[jj];
}

__global__ __launch_bounds__(256) void wkv_pass2(
    float* __restrict__ Sbuf, const float* __restrict__ Dbuf)
{
  const int bh = blockIdx.x >> 4;
  const int f  = ((blockIdx.x & 15) << 8) + threadIdx.x;   // 0..4095
  const int j = f >> 6;
  float cur = 0.f;
  const long sbase = (long)bh * NCH_ * 4096 + f;
  const long dbase = (long)bh * NCH_ * 64 + j;
  for (int c = 0; c < NCH_-1; c++){
    float* Sp = Sbuf + sbase + (long)c*4096;
    const float tmp = *Sp;
    *Sp = cur;
    cur = fmaf(Dbuf[dbase + (long)c*64], cur, tmp);
  }
  Sbuf[sbase + (long)(NCH_-1)*4096] = cur;
}

__global__ __launch_bounds__(256) void wkv_pass3(
    const u16* __restrict__ r, const u16* __restrict__ k, const u16* __restrict__ v,
    const float* __restrict__ dec, const float* __restrict__ faaaa,
    const float* __restrict__ gam, const float* __restrict__ bet,
    const u16* __restrict__ g, u16* __restrict__ act,
    const float* __restrict__ Sbuf)
{
  const int blk = blockIdx.x;            // bh*NCH_ + c
  const int c  = blk & (NCH_-1);
  const int bh = blk >> 4;
  const int b = bh >> 5, h = bh & 31;
  const int tid = threadIdx.x;
  const int wv = tid >> 6, lane = tid & 63;
  const int hoff = h * 64;
  const int joff = wv * 16;

  // W^ state: wave wv owns j in [joff, joff+16), lane = i
  float W[16];
  {
    const float* Sp = Sbuf + (long)blk*4096 + (long)joff*64 + lane;
    #pragma unroll
    for (int jj=0;jj<16;jj++) W[jj] = Sp[jj*64];
  }
  const float uu  = faaaa[hoff + lane];       // phase A uses lane = j
  const float gmv = gam[hoff + lane], btv = bet[hoff + lane];

  __shared__ float rhat[32][64];   // 8KB
  __shared__ float ktil[32][64];   // 8KB
  __shared__ u16   vsh[32][64];    // 4KB
  __shared__ float yred[16][4][64];// 16KB
  __shared__ float Gp[4][64];      // 1KB
  __shared__ float cendL[64];
  __shared__ float ud[32];

  const long base0 = ((long)b * T_) * C_ + hoff;
  const int tA = c * TC_;

  for (int sc = 0; sc < TC_/32; ++sc){
    const int t0 = tA + sc*32;
    __syncthreads();   // guard: vsh/rhat/ktil/ud reuse vs prev sub-chunk
    // stage v[32][64] bf16: wave wv covers rows wv*8..wv*8+7 (1KB/wave)
    async_copy16(v + base0 + (long)(t0 + wv*8 + (lane>>3))*C_ + (lane&7)*8,
                 &vsh[wv*8][0]);
    // ---- phase A part 1: d loads + per-wave 8-step product (lane = j) ----
    float dloc[8];
    float gp = 1.f;
    #pragma unroll
    for (int tau=0; tau<8; ++tau){
      dloc[tau] = dec[base0 + (long)(t0 + wv*8 + tau)*C_ + lane];
      gp *= dloc[tau];
    }
    Gp[wv][lane] = gp;
    __syncthreads();
    // ---- phase A part 2: cross-wave exclusive prefix; rhat/ktil/ud ----
    float cpre = 1.f;
    #pragma unroll
    for (int gg=0; gg<4; ++gg) if (gg < wv) cpre *= Gp[gg][lane];
    if (wv == 0)
      cendL[lane] = Gp[0][lane]*Gp[1][lane]*Gp[2][lane]*Gp[3][lane];
    {
      float cc = cpre;                         // c~_{t-1} (exclusive)
      #pragma unroll
      for (int tau=0; tau<8; ++tau){
        const int tl = wv*8 + tau;
        const long gi = base0 + (long)(t0 + tl)*C_ + lane;
        const float rv = b2f(r[gi]);
        const float kv = b2f(k[gi]);
        rhat[tl][lane] = rv * cc;
        float z = rv * uu * kv;
        cc *= dloc[tau];                       // c~_t (inclusive)
        ktil[tl][lane] = kv / cc;
        #pragma unroll
        for (int off=32; off>0; off>>=1) z += __shfl_xor(z, off, 64);
        if (lane == 0) ud[tl] = z;
      }
    }
    __syncthreads();   // rhat/ktil/ud/cendL ready; drains vsh copy

    // ---- phase B: 2-fma inner loop, two halves of 16 t ----
    #pragma unroll
    for (int half=0; half<2; ++half){
      #pragma unroll 2
      for (int tt=0; tt<16; ++tt){
        const int tl = half*16 + tt;
        float rv[16], kt[16];
        #pragma unroll
        for (int q=0;q<4;q++){
          *(float4*)(rv+q*4) = *(const float4*)&rhat[tl][joff+q*4];
          *(float4*)(kt+q*4) = *(const float4*)&ktil[tl][joff+q*4];
        }
        const float vi = b2f(vsh[tl][lane]);
        float yp = 0.f;
        #pragma unroll
        for (int jj=0;jj<16;jj++){
          yp = fmaf(rv[jj], W[jj], yp);        // y uses W^ BEFORE t-update
          W[jj] = fmaf(kt[jj], vi, W[jj]);
        }
        yred[tt][wv][lane] = yp;
      }
      __syncthreads();
      // combine + u-diag + groupnorm + *g : wave handles 4 timesteps
      #pragma unroll
      for (int q=0;q<4;q++){
        const int tt = wv*4 + q;
        const int tl = half*16 + tt;
        const float y = yred[tt][0][lane] + yred[tt][1][lane]
                      + yred[tt][2][lane] + yred[tt][3][lane]
                      + ud[tl] * b2f(vsh[tl][lane]);
        float s1 = y, s2 = y*y;
        #pragma unroll
        for (int off=32; off>0; off>>=1){
          s1 += __shfl_xor(s1, off, 64);
          s2 += __shfl_xor(s2, off, 64);
        }
        const float mean = s1 * (1.f/64.f);
        const float var  = s2 * (1.f/64.f) - mean*mean;
        const float yn   = (y - mean) * rsqrtf(var + 6.4e-4f);  // EPS = 1e-5*8^2
        const long  oi   = base0 + (long)(t0 + tl) * C_ + lane;
        const float o    = (yn * gmv + btv) * b2f(g[oi]);
        act[oi] = f2b(o);
      }
      if (half == 0) __syncthreads();          // yred reuse guard for half 1
    }
    // exact state handoff: S = c~_32 (.) W^
    #pragma unroll
    for (int jj=0;jj<16;jj++) W[jj] *= cendL[joff + jj];
  }
}

extern "C" void kernel_launch(void* const* d_in, const int* in_sizes, int n_in,
                              void* d_out, int out_size, void* d_ws, size_t ws_size,
                              hipStream_t stream)
{
  const float* x     = (const float*)d_in[0];
  const float* tmx   = (const float*)d_in[1];
  const float* maaf[5] = {(const float*)d_in[2], (const float*)d_in[3],
                          (const float*)d_in[4], (const float*)d_in[5],
                          (const float*)d_in[6]};
  const float* w1    = (const float*)d_in[7];
  const float* w2    = (const float*)d_in[8];
  const float* td    = (const float*)d_in[9];
  const float* tdw1  = (const float*)d_in[10];
  const float* tdw2  = (const float*)d_in[11];
  const float* faaaa = (const float*)d_in[12];
  const float* Wmat[5] = {(const float*)d_in[13], (const float*)d_in[14],
                          (const float*)d_in[15], (const float*)d_in[16],
                          (const float*)d_in[17]};   // W_r, W_k, W_v, W_g, W_o
  const float* ln_g  = (const float*)d_in[18];
  const float* ln_b  = (const float*)d_in[19];

  // ---- workspace layout ----
  char* p = (char*)d_ws;
  auto take = [&](size_t bytes)->char*{
    char* q = p; p += (bytes + 255) & ~(size_t)255; return q;
  };
  u16*   w1t  = (u16*)take(256L*2048*2);     // (256 x 2048), rows>=160 zero
  u16*   w2t  = (u16*)take(5L*2048*32*2);    // 5 x (2048 x 32)
  u16*   wd1t = (u16*)take(128L*2048*2);     // (128 x 2048), rows>=64 zero
  u16*   wd2t = (u16*)take(2048L*64*2);      // (2048 x 64)
  u16*   wcur = (u16*)take(WELE*2);          // current weight, bf16 (reused 5x)
  u16*   xxx  = (u16*)take(BTC*2);           // xxx; aliased as mixbuf, then Sbuf
  u16*   xxb  = (u16*)take(BTC*2);           // xx;  aliased as rbuf (r done last)
  u16*   abuf = (u16*)take((long)BT_*256*2); // a = tanh(xxx@w1)
  u16*   hbuf = (u16*)take((long)BT_*128*2); // tanh(xw@tdw1); aliased as Dbuf
  u16*   kbuf = (u16*)take(BTC*2);           // aliased as act
  u16*   vbuf = (u16*)take(BTC*2);
  u16*   gbuf = (u16*)take(BTC*2);
  u16*   mixbuf = xxx;            // xxx dead after a-GEMM
  u16*   rbuf   = xxb;            // xxb dead after mix-r epilogue
  u16*   act    = kbuf;           // pass3 block reads its k rows before writing
  float* dcy    = (float*)d_out;  // fp32 decay; d_out dead until decay-GEMM
  u16*   xbf    = (u16*)d_out;    // bf16 x (33.5MB) in d_out until decay-GEMM
  float* Sbuf   = (float*)mixbuf; // 2048*4096*4 B = BTC*2 exactly
  float* Dbuf   = (float*)hbuf;   // 512KB; dead after decay GEMM
  (void)in_sizes; (void)n_in; (void)out_size; (void)ws_size;

  // small-weight prep
  tposeA <<<2048, 256, 0, stream>>>(w1,   w1t,  2048, 160, 256);
  tposeW2<<<1280, 256, 0, stream>>>(w2,   w2t);
  tposeA <<<1024, 256, 0, stream>>>(tdw1, wd1t, 2048, 64, 128);
  tposeA <<<512,  256, 0, stream>>>(tdw2, wd2t, 64, 2048, 2048);

  // token shift (+ bf16 x copy into d_out)
  mixA<<<16384, 256, 0, stream>>>(x, tmx, xxx, xxb, xbf);

  // a = tanh(xxx @ w1)   (M=8192, N=256(pad), K=2048) -- 64-row tiles (R10)
  gemm_bt64<EPI_TANH><<<dim3(2,128), 256, 0, stream>>>(xxx, 2048, w1t, 2048, 2048,
      abuf, 256);

  // ---- f = k ----
  gemm_bt<EPI_MIX><<<dim3(16,64), 256, 0, stream>>>(abuf + 1*32, 256,
      w2t + 1L*65536, 32, 32, mixbuf, 2048, (const float*)xbf, xxb, maaf[1]);
  cvt1<<<4096, 256, 0, stream>>>(Wmat[1], wcur);
  gemm256<EPI_BF16><<<dim3(8,32), 512, 0, stream>>>(mixbuf, wcur, kbuf, 2048);

  // ---- f = v ----
  gemm_bt<EPI_MIX><<<dim3(16,64), 256, 0, stream>>>(abuf + 2*32, 256,
      w2t + 2L*65536, 32, 32, mixbuf, 2048, (const float*)xbf, xxb, maaf[2]);
  cvt1<<<4096, 256, 0, stream>>>(Wmat[2], wcur);
  gemm256<EPI_BF16><<<dim3(8,32), 512, 0, stream>>>(mixbuf, wcur, vbuf, 2048);

  // ---- f = g ----
  gemm_bt<EPI_MIX><<<dim3(16,64), 256, 0, stream>>>(abuf + 4*32, 256,
      w2t + 4L*65536, 32, 32, mixbuf, 2048, (const float*)xbf, xxb, maaf[4]);
  cvt1<<<4096, 256, 0, stream>>>(Wmat[3], wcur);
  gemm256<EPI_SILU><<<dim3(8,32), 512, 0, stream>>>(mixbuf, wcur, gbuf, 2048);

  // ---- f = w (mix + tanh GEMM; hbuf holds tanh result) -- 64-row tiles ----
  gemm_bt<EPI_MIX><<<dim3(16,64), 256, 0, stream>>>(abuf + 0*32, 256,
      w2t + 0L*65536, 32, 32, mixbuf, 2048, (const float*)xbf, xxb, maaf[0]);
  gemm_bt64<EPI_TANH><<<dim3(1,128), 256, 0, stream>>>(mixbuf, 2048, wd1t, 2048, 2048,
      hbuf, 128);

  // ---- f = r (frees xxb for rbuf; xbf dead after this mix) ----
  gemm_bt<EPI_MIX><<<dim3(16,64), 256, 0, stream>>>(abuf + 3*32, 256,
      w2t + 3L*65536, 32, 32, mixbuf, 2048, (const float*)xbf, xxb, maaf[3]);
  cvt1<<<4096, 256, 0, stream>>>(Wmat[0], wcur);
  gemm256<EPI_BF16><<<dim3(8,32), 512, 0, stream>>>(mixbuf, wcur, rbuf, 2048);

  // ---- decay = exp(-exp(...)) -> d_out (clobbers xbf, now dead) ----
  gemm_bt<EPI_DECAY><<<dim3(16,64), 256, 0, stream>>>(hbuf, 128, wd2t, 64, 64,
      dcy, 2048, td, nullptr, nullptr);

  // ---- wkv: chunk-parallel scan (exact) + groupnorm + *g ----
  wkv_pass1<<<128*NCH_, 256, 0, stream>>>(kbuf, vbuf, dcy, Sbuf, Dbuf);
  wkv_pass2<<<128*NCH_, 256, 0, stream>>>(Sbuf, Dbuf);
  wkv_pass3<<<128*NCH_, 256, 0, stream>>>(rbuf, kbuf, vbuf, dcy, faaaa,
      ln_g, ln_b, gbuf, act, Sbuf);

  // ---- out = act @ W_o^T (fp32) ----
  cvt1<<<4096, 256, 0, stream>>>(Wmat[4], wcur);
  gemm256<EPI_F32><<<dim3(8,32), 512, 0, stream>>>(act, wcur, d_out, 2048);
}

// Round 11
// 972.181 us; speedup vs baseline: 1.0694x; 1.0694x over previous
//
#include <hip/hip_runtime.h>
#include <hip/hip_bf16.h>
#include <math.h>

#define B_ 4
#define T_ 2048
#define C_ 2048
#define H_ 32
#define BT_ 8192
#define WELE 4194304L            // 2048*2048
#define BTC  16777216L           // 8192*2048
#define NCH_ 16                  // chunks along T for wkv parallel scan
#define TC_  128                 // T_/NCH_
#define GNT  32                  // K/64 for the 256^2 GEMM (K=2048)

typedef unsigned short u16;
typedef __bf16 bf16x8 __attribute__((ext_vector_type(8)));
typedef float  f32x4  __attribute__((ext_vector_type(4)));

__device__ __forceinline__ u16 f2b(float f){
  __hip_bfloat16 h = __float2bfloat16(f);
  return *reinterpret_cast<u16*>(&h);
}
__device__ __forceinline__ float b2f(u16 u){
  __hip_bfloat16 h; *reinterpret_cast<u16*>(&h) = u;
  return __bfloat162float(h);
}
__device__ __forceinline__ float bits2f(unsigned u){
  union { unsigned u; float f; } c; c.u = u; return c.f;
}

__device__ __forceinline__ void async_copy16(const u16* gptr, u16* lptr){
  __builtin_amdgcn_global_load_lds(
      (const __attribute__((address_space(1))) unsigned int*)gptr,
      (__attribute__((address_space(3))) unsigned int*)lptr,
      16, 0, 0);
}

// unpack 4 consecutive bf16 at gp into 4 floats
__device__ __forceinline__ void unpack4(const u16* __restrict__ gp, float* out){
  const uint2 raw = *(const uint2*)gp;
  out[0] = bits2f(raw.x << 16); out[1] = bits2f(raw.x & 0xffff0000u);
  out[2] = bits2f(raw.y << 16); out[3] = bits2f(raw.y & 0xffff0000u);
}

// ---------------- weight prep ----------------
__global__ __launch_bounds__(256) void cvt1(const float* __restrict__ src,
                                            u16* __restrict__ dst)
{
  const long i = ((long)blockIdx.x*256 + threadIdx.x)*4;
  const float4 v = *(const float4*)(src + i);
  ushort4 o = { f2b(v.x), f2b(v.y), f2b(v.z), f2b(v.w) };
  *(ushort4*)(dst + i) = o;
}

__global__ __launch_bounds__(256) void tposeA(const float* __restrict__ src,
    u16* __restrict__ dst, int R, int Cc, int Npad)
{
  const long idx = (long)blockIdx.x*256 + threadIdx.x;
  if (idx >= (long)Npad * R) return;
  const int n = (int)(idx / R), rr = (int)(idx % R);
  float vv = (n < Cc) ? src[(long)rr * Cc + n] : 0.f;
  dst[idx] = f2b(vv);
}

__global__ __launch_bounds__(256) void tposeW2(const float* __restrict__ src,
                                               u16* __restrict__ dst)
{
  const long idx = (long)blockIdx.x*256 + threadIdx.x; // < 5*2048*32
  const int f = (int)(idx / 65536);
  const int rem = (int)(idx % 65536);
  const int c = rem >> 5, d = rem & 31;
  dst[idx] = f2b(src[((long)f*32 + d)*2048 + c]);
}

// ---------------- token shift / xxx ----------------
__global__ __launch_bounds__(256) void mixA(const float* __restrict__ x,
    const float* __restrict__ maax, u16* __restrict__ xxx, u16* __restrict__ xxb,
    u16* __restrict__ xbf)
{
  const long i = ((long)blockIdx.x*256 + threadIdx.x) * 4;
  const int c   = (int)(i & (C_-1));
  const int tok = (int)(i >> 11);
  const int t   = tok & (T_-1);
  const float4 xc = *(const float4*)(x + i);
  float4 xp = make_float4(0.f,0.f,0.f,0.f);
  if (t > 0) xp = *(const float4*)(x + i - C_);
  const float4 mx = *(const float4*)(maax + c);
  const float xx0 = xp.x - xc.x, xx1 = xp.y - xc.y;
  const float xx2 = xp.z - xc.z, xx3 = xp.w - xc.w;
  ushort4 ox = { f2b(xx0), f2b(xx1), f2b(xx2), f2b(xx3) };
  ushort4 o3 = { f2b(fmaf(xx0, mx.x, xc.x)), f2b(fmaf(xx1, mx.y, xc.y)),
                 f2b(fmaf(xx2, mx.z, xc.z)), f2b(fmaf(xx3, mx.w, xc.w)) };
  ushort4 oxb = { f2b(xc.x), f2b(xc.y), f2b(xc.z), f2b(xc.w) };
  *(ushort4*)(xxb + i) = ox;
  *(ushort4*)(xxx + i) = o3;
  *(ushort4*)(xbf + i) = oxb;
}

// ---------------- GEMM epilogues ----------------
enum { EPI_BF16=0, EPI_TANH=1, EPI_SILU=2, EPI_MIX=3, EPI_DECAY=4, EPI_F32=5 };

// ---------------- small GEMM (128^2 tile): K<=64 / N<=256 cases ----------
template<int EPI>
__global__ __launch_bounds__(256) void gemm_bt(
    const u16* __restrict__ A, int lda,
    const u16* __restrict__ Bm, int ldb, int K,
    void* __restrict__ Out, int ldo,
    const float* __restrict__ aux0, const u16* __restrict__ aux1,
    const float* __restrict__ aux2)
{
  __shared__ u16 As[128*32];
  __shared__ u16 Bs[128*32];
  const int tid = threadIdx.x;
  const int w = tid >> 6, lane = tid & 63;
  const int m0 = blockIdx.y * 128, n0 = blockIdx.x * 128;
  const int wm = w >> 1, wn = w & 1;
  const int rowA = lane >> 2, chunk = lane & 3;
  f32x4 acc[4][4];
  #pragma unroll
  for (int i=0;i<4;i++)
    #pragma unroll
    for (int j=0;j<4;j++) acc[i][j] = (f32x4){0.f,0.f,0.f,0.f};

  for (int k0 = 0; k0 < K; k0 += 32){
    #pragma unroll
    for (int s=0; s<2; s++){
      const int seg = w*2 + s;
      const int row = seg*16 + rowA;
      async_copy16(A  + (long)(m0+row)*lda + k0 + chunk*8, As + seg*512);
      async_copy16(Bm + (long)(n0+row)*ldb + k0 + chunk*8, Bs + seg*512);
    }
    __syncthreads();
    const int kq = (lane >> 4) * 8;
    const int lr16 = lane & 15;
    bf16x8 af[4], bfr[4];
    #pragma unroll
    for (int mt=0; mt<4; mt++)
      af[mt] = *(const bf16x8*)(As + (wm*64 + mt*16 + lr16)*32 + kq);
    #pragma unroll
    for (int nt=0; nt<4; nt++)
      bfr[nt] = *(const bf16x8*)(Bs + (wn*64 + nt*16 + lr16)*32 + kq);
    #pragma unroll
    for (int mt=0; mt<4; mt++)
      #pragma unroll
      for (int nt=0; nt<4; nt++)
        acc[mt][nt] = __builtin_amdgcn_mfma_f32_16x16x32_bf16(af[mt], bfr[nt], acc[mt][nt], 0, 0, 0);
    __syncthreads();
  }

  const int cr = lane & 15, cq = lane >> 4;
  #pragma unroll
  for (int mt=0; mt<4; mt++){
    #pragma unroll
    for (int nt=0; nt<4; nt++){
      #pragma unroll
      for (int rr=0; rr<4; rr++){
        const int row = m0 + wm*64 + mt*16 + cq*4 + rr;
        const int col = n0 + wn*64 + nt*16 + cr;
        const long oi = (long)row*ldo + col;
        const float val = acc[mt][nt][rr];
        if constexpr (EPI == EPI_F32){
          ((float*)Out)[oi] = val;
        } else if constexpr (EPI == EPI_BF16){
          ((u16*)Out)[oi] = f2b(val);
        } else if constexpr (EPI == EPI_TANH){
          ((u16*)Out)[oi] = f2b(tanhf(val));
        } else if constexpr (EPI == EPI_SILU){
          ((u16*)Out)[oi] = f2b(val / (1.f + expf(-val)));
        } else if constexpr (EPI == EPI_MIX){
          const float xv  = b2f(((const u16*)aux0)[oi]);   // bf16 x (R6)
          const float xxv = b2f(aux1[oi]);
          ((u16*)Out)[oi] = f2b(fmaf(xxv, aux2[col] + val, xv));
        } else { // EPI_DECAY
          ((float*)Out)[oi] = expf(-expf(val + aux0[col]));
        }
      }
    }
  }
}

// ---------------- big GEMM: 256^2 tile, BK=64, phase-pipelined --------------
// (unchanged from R4: best-measured config)
template<int EPI>
__global__ __launch_bounds__(512) void gemm256(
    const u16* __restrict__ A, const u16* __restrict__ Bm,
    void* __restrict__ Out, int ldo)
{
  __shared__ u16 lds[65536];     // [A buf0][A buf1][B buf0][B buf1], 16384 each
  const int tid  = threadIdx.x;
  const int w    = tid >> 6, lane = tid & 63;
  const int wm   = w >> 2, wn = w & 3;           // 2 x 4 waves
  const long m0  = (long)blockIdx.y * 256;
  const long n0  = (long)blockIdx.x * 256;

  auto stage_half = [&](u16* ldsbase, const u16* gb){
    const int rsub = lane >> 3;                  // 0..7
    const int c16  = (lane & 7) ^ rsub;          // inverse swizzle (involution)
    #pragma unroll
    for (int r2 = 0; r2 < 2; ++r2){
      const int row = (r2*8 + w)*8 + rsub;
      async_copy16(gb + (long)row*2048 + c16*8,
                   ldsbase + (r2*8 + w)*512);
    }
  };
  auto stage = [&](int t, int half){
    if (t >= GNT) return;
    const int b = t & 1;
    const long k0 = (long)t * 64;
    if      (half == 0) stage_half(lds + 32768 + b*16384,        Bm + n0*2048 + k0);
    else if (half == 1) stage_half(lds + 32768 + b*16384 + 8192, Bm + (n0+128)*2048 + k0);
    else if (half == 2) stage_half(lds + b*16384,                A  + m0*2048 + k0);
    else                stage_half(lds + b*16384 + 8192,         A  + (m0+128)*2048 + k0);
  };

  const int lr16 = lane & 15;
  const int kq   = lane >> 4;                    // 0..3
  auto aslot = [&](int buf, int row, int c16)->const u16*{
    return lds + buf*16384 + row*64 + ((c16 ^ (row & 7)) << 3);
  };
  auto bslot = [&](int buf, int row, int c16)->const u16*{
    return lds + 32768 + buf*16384 + row*64 + ((c16 ^ (row & 7)) << 3);
  };

  f32x4 acc[8][4];
  #pragma unroll
  for (int i=0;i<8;i++)
    #pragma unroll
    for (int j=0;j<4;j++) acc[i][j] = (f32x4){0.f,0.f,0.f,0.f};

  stage(0,0); stage(0,1); stage(0,2); stage(0,3);
  stage(1,0); stage(1,1); stage(1,2);
  asm volatile("s_waitcnt vmcnt(6)");
  asm volatile("" ::: "memory");
  __builtin_amdgcn_s_barrier();

  for (int t = 0; t < GNT; ++t){
    const int buf = t & 1;
    bf16x8 bfr[4][2];
    #pragma unroll
    for (int p = 0; p < 4; ++p){
      if (p == 0){
        #pragma unroll
        for (int nt=0; nt<4; nt++)
          #pragma unroll
          for (int kk=0; kk<2; kk++)
            bfr[nt][kk] = *(const bf16x8*)bslot(buf, wn*64 + nt*16 + lr16, kk*4 + kq);
      }
      bf16x8 af[2][2];
      #pragma unroll
      for (int i=0; i<2; i++)
        #pragma unroll
        for (int kk=0; kk<2; kk++)
          af[i][kk] = *(const bf16x8*)aslot(buf, wm*128 + (2*p+i)*16 + lr16, kk*4 + kq);
      if (p == 0) stage(t+1, 3);
      else        stage(t+2, p-1);
      if (p == 3){
        if (t <= GNT-3) asm volatile("s_waitcnt vmcnt(6)");
        else            asm volatile("s_waitcnt vmcnt(0)");
      }
      asm volatile("" ::: "memory");
      __builtin_amdgcn_s_barrier();
      __builtin_amdgcn_s_setprio(1);
      #pragma unroll
      for (int i=0; i<2; i++)
        #pragma unroll
        for (int nt=0; nt<4; nt++)
          #pragma unroll
          for (int kk=0; kk<2; kk++)
            acc[2*p+i][nt] = __builtin_amdgcn_mfma_f32_16x16x32_bf16(
                af[i][kk], bfr[nt][kk], acc[2*p+i][nt], 0, 0, 0);
      __builtin_amdgcn_s_setprio(0);
    }
  }

  const int cr = lane & 15, cq = lane >> 4;
  #pragma unroll
  for (int mt=0; mt<8; mt++){
    #pragma unroll
    for (int nt=0; nt<4; nt++){
      #pragma unroll
      for (int rr=0; rr<4; rr++){
        const long row = m0 + wm*128 + mt*16 + cq*4 + rr;
        const long col = n0 + wn*64 + nt*16 + cr;
        const long oi  = row*ldo + col;
        const float val = acc[mt][nt][rr];
        if constexpr (EPI == EPI_F32){
          ((float*)Out)[oi] = val;
        } else if constexpr (EPI == EPI_BF16){
          ((u16*)Out)[oi] = f2b(val);
        } else { // EPI_SILU
          ((u16*)Out)[oi] = f2b(val / (1.f + expf(-val)));
        }
      }
    }
  }
}

// ---------------- WKV6: exact chunk-parallel scan ----------------
// pass1/pass2 from R5; pass3 = R7 2-fma scan (best measured; 4-fma/2-fma/MFMA
// all land within +-5% of ~172us -> latency-structure-bound, declared done).

__global__ __launch_bounds__(256) void wkv_pass1(
    const u16* __restrict__ k, const u16* __restrict__ v,
    const float* __restrict__ dec,
    float* __restrict__ Sbuf, float* __restrict__ Dbuf)
{
  const int blk = blockIdx.x;            // bh*NCH_ + c
  const int c  = blk & (NCH_-1);
  if (c == NCH_-1) return;               // last chunk's S_loc/D never used
  const int bh = blk >> 4;
  const int b = bh >> 5, h = bh & 31;
  const int tid = threadIdx.x;
  const int g = tid >> 6, lane = tid & 63;   // phase A: lane = channel j, g = t-group
  const int hoff = h * 64;
  const long base0 = ((long)b * T_) * C_ + hoff;
  const int tA = c * TC_;

  __shared__ float kts[128][64];   // kappa~[t][j] = k*suffix, fp32 (32KB)
  __shared__ u16   vsh[128][64];   // raw bf16 v (16KB)
  __shared__ float Gp[4][64];      // 32-step group products

  #pragma unroll
  for (int rd = 0; rd < 4; ++rd){
    const int row0 = (rd*4 + g) * 8;
    async_copy16(v + base0 + (long)(tA + row0 + (lane>>3))*C_ + (lane&7)*8,
                 &vsh[row0][0]);
  }

  float d[32];
  float gp = 1.f;
  #pragma unroll
  for (int tau = 0; tau < 32; ++tau){
    d[tau] = dec[base0 + (long)(tA + g*32 + tau)*C_ + lane];
    gp *= d[tau];
  }
  Gp[g][lane] = gp;
  __syncthreads();
  float CS = 1.f;
  #pragma unroll
  for (int gg = 0; gg < 4; ++gg)
    if (gg > g) CS *= Gp[gg][lane];
  if (g == 0){
    Dbuf[(long)blk*64 + lane] =
        Gp[0][lane]*Gp[1][lane]*Gp[2][lane]*Gp[3][lane];
  }
  {
    float R = CS;
    #pragma unroll
    for (int tau = 31; tau >= 0; --tau){
      const float kv = b2f(k[base0 + (long)(tA + g*32 + tau)*C_ + lane]);
      kts[g*32 + tau][lane] = kv * R;
      R *= d[tau];
    }
  }
  __syncthreads();

  const int joff = g * 16;
  float S[16];
  #pragma unroll
  for (int jj=0;jj<16;jj++) S[jj]=0.f;
  #pragma unroll 4
  for (int t = 0; t < TC_; ++t){
    float kv[16];
    #pragma unroll
    for (int q=0;q<4;q++)
      *(float4*)(kv+q*4) = *(const float4*)&kts[t][joff+q*4];
    const float vi = b2f(vsh[t][lane]);
    #pragma unroll
    for (int jj=0;jj<16;jj++)
      S[jj] = fmaf(kv[jj], vi, S[jj]);
  }
  float* Sp = Sbuf + (long)blk*4096 + (long)joff*64 + lane;
  #pragma unroll
  for (int jj=0;jj<16;jj++) Sp[jj*64] = S[jj];
}

__global__ __launch_bounds__(256) void wkv_pass2(
    float* __restrict__ Sbuf, const float* __restrict__ Dbuf)
{
  const int bh = blockIdx.x >> 4;
  const int f  = ((blockIdx.x & 15) << 8) + threadIdx.x;   // 0..4095
  const int j = f >> 6;
  float cur = 0.f;
  const long sbase = (long)bh * NCH_ * 4096 + f;
  const long dbase = (long)bh * NCH_ * 64 + j;
  for (int c = 0; c < NCH_-1; c++){
    float* Sp = Sbuf + sbase + (long)c*4096;
    const float tmp = *Sp;
    *Sp = cur;
    cur = fmaf(Dbuf[dbase + (long)c*64], cur, tmp);
  }
  Sbuf[sbase + (long)(NCH_-1)*4096] = cur;
}

__global__ __launch_bounds__(256) void wkv_pass3(
    const u16* __restrict__ r, const u16* __restrict__ k, const u16* __restrict__ v,
    const float* __restrict__ dec, const float* __restrict__ faaaa,
    const float* __restrict__ gam, const float* __restrict__ bet,
    const u16* __restrict__ g, u16* __restrict__ act,
    const float* __restrict__ Sbuf)
{
  const int blk = blockIdx.x;            // bh*NCH_ + c
  const int c  = blk & (NCH_-1);
  const int bh = blk >> 4;
  const int b = bh >> 5, h = bh & 31;
  const int tid = threadIdx.x;
  const int wv = tid >> 6, lane = tid & 63;
  const int hoff = h * 64;
  const int joff = wv * 16;

  // W^ state: wave wv owns j in [joff, joff+16), lane = i
  float W[16];
  {
    const float* Sp = Sbuf + (long)blk*4096 + (long)joff*64 + lane;
    #pragma unroll
    for (int jj=0;jj<16;jj++) W[jj] = Sp[jj*64];
  }
  const float uu  = faaaa[hoff + lane];       // phase A uses lane = j
  const float gmv = gam[hoff + lane], btv = bet[hoff + lane];

  __shared__ float rhat[32][64];   // 8KB
  __shared__ float ktil[32][64];   // 8KB
  __shared__ u16   vsh[32][64];    // 4KB
  __shared__ float yred[16][4][64];// 16KB
  __shared__ float Gp[4][64];      // 1KB
  __shared__ float cendL[64];
  __shared__ float ud[32];

  const long base0 = ((long)b * T_) * C_ + hoff;
  const int tA = c * TC_;

  for (int sc = 0; sc < TC_/32; ++sc){
    const int t0 = tA + sc*32;
    __syncthreads();   // guard: vsh/rhat/ktil/ud reuse vs prev sub-chunk
    // stage v[32][64] bf16: wave wv covers rows wv*8..wv*8+7 (1KB/wave)
    async_copy16(v + base0 + (long)(t0 + wv*8 + (lane>>3))*C_ + (lane&7)*8,
                 &vsh[wv*8][0]);
    // ---- phase A part 1: d loads + per-wave 8-step product (lane = j) ----
    float dloc[8];
    float gp = 1.f;
    #pragma unroll
    for (int tau=0; tau<8; ++tau){
      dloc[tau] = dec[base0 + (long)(t0 + wv*8 + tau)*C_ + lane];
      gp *= dloc[tau];
    }
    Gp[wv][lane] = gp;
    __syncthreads();
    // ---- phase A part 2: cross-wave exclusive prefix; rhat/ktil/ud ----
    float cpre = 1.f;
    #pragma unroll
    for (int gg=0; gg<4; ++gg) if (gg < wv) cpre *= Gp[gg][lane];
    if (wv == 0)
      cendL[lane] = Gp[0][lane]*Gp[1][lane]*Gp[2][lane]*Gp[3][lane];
    {
      float cc = cpre;                         // c~_{t-1} (exclusive)
      #pragma unroll
      for (int tau=0; tau<8; ++tau){
        const int tl = wv*8 + tau;
        const long gi = base0 + (long)(t0 + tl)*C_ + lane;
        const float rv = b2f(r[gi]);
        const float kv = b2f(k[gi]);
        rhat[tl][lane] = rv * cc;
        float z = rv * uu * kv;
        cc *= dloc[tau];                       // c~_t (inclusive)
        ktil[tl][lane] = kv / cc;
        #pragma unroll
        for (int off=32; off>0; off>>=1) z += __shfl_xor(z, off, 64);
        if (lane == 0) ud[tl] = z;
      }
    }
    __syncthreads();   // rhat/ktil/ud/cendL ready; drains vsh copy

    // ---- phase B: 2-fma inner loop, two halves of 16 t ----
    #pragma unroll
    for (int half=0; half<2; ++half){
      #pragma unroll 2
      for (int tt=0; tt<16; ++tt){
        const int tl = half*16 + tt;
        float rv[16], kt[16];
        #pragma unroll
        for (int q=0;q<4;q++){
          *(float4*)(rv+q*4) = *(const float4*)&rhat[tl][joff+q*4];
          *(float4*)(kt+q*4) = *(const float4*)&ktil[tl][joff+q*4];
        }
        const float vi = b2f(vsh[tl][lane]);
        float yp = 0.f;
        #pragma unroll
        for (int jj=0;jj<16;jj++){
          yp = fmaf(rv[jj], W[jj], yp);        // y uses W^ BEFORE t-update
          W[jj] = fmaf(kt[jj], vi, W[jj]);
        }
        yred[tt][wv][lane] = yp;
      }
      __syncthreads();
      // combine + u-diag + groupnorm + *g : wave handles 4 timesteps
      #pragma unroll
      for (int q=0;q<4;q++){
        const int tt = wv*4 + q;
        const int tl = half*16 + tt;
        const float y = yred[tt][0][lane] + yred[tt][1][lane]
                      + yred[tt][2][lane] + yred[tt][3][lane]
                      + ud[tl] * b2f(vsh[tl][lane]);
        float s1 = y, s2 = y*y;
        #pragma unroll
        for (int off=32; off>0; off>>=1){
          s1 += __shfl_xor(s1, off, 64);
          s2 += __shfl_xor(s2, off, 64);
        }
        const float mean = s1 * (1.f/64.f);
        const float var  = s2 * (1.f/64.f) - mean*mean;
        const float yn   = (y - mean) * rsqrtf(var + 6.4e-4f);  // EPS = 1e-5*8^2
        const long  oi   = base0 + (long)(t0 + tl) * C_ + lane;
        const float o    = (yn * gmv + btv) * b2f(g[oi]);
        act[oi] = f2b(o);
      }
      if (half == 0) __syncthreads();          // yred reuse guard for half 1
    }
    // exact state handoff: S = c~_32 (.) W^
    #pragma unroll
    for (int jj=0;jj<16;jj++) W[jj] *= cendL[joff + jj];
  }
}

extern "C" void kernel_launch(void* const* d_in, const int* in_sizes, int n_in,
                              void* d_out, int out_size, void* d_ws, size_t ws_size,
                              hipStream_t stream)
{
  const float* x     = (const float*)d_in[0];
  const float* tmx   = (const float*)d_in[1];
  const float* maaf[5] = {(const float*)d_in[2], (const float*)d_in[3],
                          (const float*)d_in[4], (const float*)d_in[5],
                          (const float*)d_in[6]};
  const float* w1    = (const float*)d_in[7];
  const float* w2    = (const float*)d_in[8];
  const float* td    = (const float*)d_in[9];
  const float* tdw1  = (const float*)d_in[10];
  const float* tdw2  = (const float*)d_in[11];
  const float* faaaa = (const float*)d_in[12];
  const float* Wmat[5] = {(const float*)d_in[13], (const float*)d_in[14],
                          (const float*)d_in[15], (const float*)d_in[16],
                          (const float*)d_in[17]};   // W_r, W_k, W_v, W_g, W_o
  const float* ln_g  = (const float*)d_in[18];
  const float* ln_b  = (const float*)d_in[19];

  // ---- workspace layout ----
  char* p = (char*)d_ws;
  auto take = [&](size_t bytes)->char*{
    char* q = p; p += (bytes + 255) & ~(size_t)255; return q;
  };
  u16*   w1t  = (u16*)take(256L*2048*2);     // (256 x 2048), rows>=160 zero
  u16*   w2t  = (u16*)take(5L*2048*32*2);    // 5 x (2048 x 32)
  u16*   wd1t = (u16*)take(128L*2048*2);     // (128 x 2048), rows>=64 zero
  u16*   wd2t = (u16*)take(2048L*64*2);      // (2048 x 64)
  u16*   wcur = (u16*)take(WELE*2);          // current weight, bf16 (reused 5x)
  u16*   xxx  = (u16*)take(BTC*2);           // xxx; aliased as mixbuf, then Sbuf
  u16*   xxb  = (u16*)take(BTC*2);           // xx;  aliased as rbuf (r done last)
  u16*   abuf = (u16*)take((long)BT_*256*2); // a = tanh(xxx@w1)
  u16*   hbuf = (u16*)take((long)BT_*128*2); // tanh(xw@tdw1); aliased as Dbuf
  u16*   kbuf = (u16*)take(BTC*2);           // aliased as act
  u16*   vbuf = (u16*)take(BTC*2);
  u16*   gbuf = (u16*)take(BTC*2);
  u16*   mixbuf = xxx;            // xxx dead after a-GEMM
  u16*   rbuf   = xxb;            // xxb dead after mix-r epilogue
  u16*   act    = kbuf;           // pass3 block reads its k rows before writing
  float* dcy    = (float*)d_out;  // fp32 decay; d_out dead until decay-GEMM
  u16*   xbf    = (u16*)d_out;    // bf16 x (33.5MB) in d_out until decay-GEMM
  float* Sbuf   = (float*)mixbuf; // 2048*4096*4 B = BTC*2 exactly
  float* Dbuf   = (float*)hbuf;   // 512KB; dead after decay GEMM
  (void)in_sizes; (void)n_in; (void)out_size; (void)ws_size;

  // small-weight prep
  tposeA <<<2048, 256, 0, stream>>>(w1,   w1t,  2048, 160, 256);
  tposeW2<<<1280, 256, 0, stream>>>(w2,   w2t);
  tposeA <<<1024, 256, 0, stream>>>(tdw1, wd1t, 2048, 64, 128);
  tposeA <<<512,  256, 0, stream>>>(tdw2, wd2t, 64, 2048, 2048);

  // token shift (+ bf16 x copy into d_out)
  mixA<<<16384, 256, 0, stream>>>(x, tmx, xxx, xxb, xbf);

  // a = tanh(xxx @ w1)   (M=8192, N=256(pad), K=2048)
  gemm_bt<EPI_TANH><<<dim3(2,64), 256, 0, stream>>>(xxx, 2048, w1t, 2048, 2048,
      abuf, 256, nullptr, nullptr, nullptr);

  // ---- f = k ----
  gemm_bt<EPI_MIX><<<dim3(16,64), 256, 0, stream>>>(abuf + 1*32, 256,
      w2t + 1L*65536, 32, 32, mixbuf, 2048, (const float*)xbf, xxb, maaf[1]);
  cvt1<<<4096, 256, 0, stream>>>(Wmat[1], wcur);
  gemm256<EPI_BF16><<<dim3(8,32), 512, 0, stream>>>(mixbuf, wcur, kbuf, 2048);

  // ---- f = v ----
  gemm_bt<EPI_MIX><<<dim3(16,64), 256, 0, stream>>>(abuf + 2*32, 256,
      w2t + 2L*65536, 32, 32, mixbuf, 2048, (const float*)xbf, xxb, maaf[2]);
  cvt1<<<4096, 256, 0, stream>>>(Wmat[2], wcur);
  gemm256<EPI_BF16><<<dim3(8,32), 512, 0, stream>>>(mixbuf, wcur, vbuf, 2048);

  // ---- f = g ----
  gemm_bt<EPI_MIX><<<dim3(16,64), 256, 0, stream>>>(abuf + 4*32, 256,
      w2t + 4L*65536, 32, 32, mixbuf, 2048, (const float*)xbf, xxb, maaf[4]);
  cvt1<<<4096, 256, 0, stream>>>(Wmat[3], wcur);
  gemm256<EPI_SILU><<<dim3(8,32), 512, 0, stream>>>(mixbuf, wcur, gbuf, 2048);

  // ---- f = w (mix + first decay GEMM; hbuf holds tanh result) ----
  gemm_bt<EPI_MIX><<<dim3(16,64), 256, 0, stream>>>(abuf + 0*32, 256,
      w2t + 0L*65536, 32, 32, mixbuf, 2048, (const float*)xbf, xxb, maaf[0]);
  gemm_bt<EPI_TANH><<<dim3(1,64), 256, 0, stream>>>(mixbuf, 2048, wd1t, 2048, 2048,
      hbuf, 128, nullptr, nullptr, nullptr);

  // ---- f = r (frees xxb for rbuf; xbf no longer needed after this mix) ----
  gemm_bt<EPI_MIX><<<dim3(16,64), 256, 0, stream>>>(abuf + 3*32, 256,
      w2t + 3L*65536, 32, 32, mixbuf, 2048, (const float*)xbf, xxb, maaf[3]);
  cvt1<<<4096, 256, 0, stream>>>(Wmat[0], wcur);
  gemm256<EPI_BF16><<<dim3(8,32), 512, 0, stream>>>(mixbuf, wcur, rbuf, 2048);

  // ---- decay = exp(-exp(...)) -> d_out (clobbers xbf, now dead) ----
  gemm_bt<EPI_DECAY><<<dim3(16,64), 256, 0, stream>>>(hbuf, 128, wd2t, 64, 64,
      dcy, 2048, td, nullptr, nullptr);

  // ---- wkv: chunk-parallel scan (exact) + groupnorm + *g ----
  wkv_pass1<<<128*NCH_, 256, 0, stream>>>(kbuf, vbuf, dcy, Sbuf, Dbuf);
  wkv_pass2<<<128*NCH_, 256, 0, stream>>>(Sbuf, Dbuf);
  wkv_pass3<<<128*NCH_, 256, 0, stream>>>(rbuf, kbuf, vbuf, dcy, faaaa,
      ln_g, ln_b, gbuf, act, Sbuf);

  // ---- out = act @ W_o^T (fp32) ----
  cvt1<<<4096, 256, 0, stream>>>(Wmat[4], wcur);
  gemm256<EPI_F32><<<dim3(8,32), 512, 0, stream>>>(act, wcur, d_out, 2048);
}